// Round 10
// baseline (388.675 us; speedup 1.0000x reference)
//
#include <hip/hip_runtime.h>
#include <cmath>

typedef unsigned short u16;
typedef __attribute__((ext_vector_type(8))) __bf16 bf16x8;
typedef __attribute__((ext_vector_type(4))) float f32x4;

constexpr int Bb = 2, Tt = 8, Dc = 128, PIX = 4096; // b=2, c=128, 64x64 imgs

__device__ inline u16 f2bf(float f) {
    unsigned u = __builtin_bit_cast(unsigned, f);
    u += 0x7fffu + ((u >> 16) & 1u);
    return (u16)(u >> 16);
}
__device__ inline float bf2f(u16 h) {
    unsigned u = ((unsigned)h) << 16;
    return __builtin_bit_cast(float, u);
}

#define GLOAD16(gp, lp) __builtin_amdgcn_global_load_lds( \
    (const __attribute__((address_space(1))) void*)(const void*)(gp), \
    (__attribute__((address_space(3))) void*)(void*)(lp), 16, 0, 0)

// ---------------------------------------------------------------------------
// bf16 NT MFMA core, 2-phase prefetch pipeline (r4).
// ---------------------------------------------------------------------------
__device__ inline void mfma_chunk(const u16* lAs, const u16* lBs, int wave, int lane,
                                  f32x4 (&acc)[4][4])
{
    const int wm = (wave >> 1) * 64, wn = (wave & 1) * 64;
    const int fr = lane & 15;
    const int q4 = lane >> 4;                         // wanted global k-quarter
    const int sw = (q4 ^ ((fr >> 1) & 3)) * 8;        // swizzled storage seg
    bf16x8 av[4], bv[4];
#pragma unroll
    for (int i = 0; i < 4; ++i) av[i] = *(const bf16x8*)&lAs[(wm + i * 16 + fr) * 32 + sw];
#pragma unroll
    for (int j = 0; j < 4; ++j) bv[j] = *(const bf16x8*)&lBs[(wn + j * 16 + fr) * 32 + sw];
#pragma unroll
    for (int i = 0; i < 4; ++i)
#pragma unroll
        for (int j = 0; j < 4; ++j)
            acc[i][j] = __builtin_amdgcn_mfma_f32_16x16x32_bf16(av[i], bv[j], acc[i][j], 0, 0, 0);
}

__device__ inline void stage_chunk(const u16* ga0, const u16* ga1,
                                   const u16* gb0, const u16* gb1,
                                   int kb, u16* lA, u16* lB, int wave)
{
    GLOAD16(ga0 + kb * 32, lA + wave * 1024);
    GLOAD16(ga1 + kb * 32, lA + wave * 1024 + 512);
    GLOAD16(gb0 + kb * 32, lB + wave * 1024);
    GLOAD16(gb1 + kb * 32, lB + wave * 1024 + 512);
}

// kChunks = number of 32-K chunks (any count >= 1).
__device__ inline void mfma_nt(const u16* A, int ldkA, const u16* B, int ldkB,
                               int kChunks, int wave, int lane,
                               u16* lAs, u16* lBs, f32x4 (&acc)[4][4])
{
    const int r = lane >> 2;                              // row within 16-group
    const int kq8 = ((lane & 3) ^ ((r >> 1) & 3)) * 8;    // swizzled source seg
    const u16* ga0 = A + (size_t)(wave * 32 + r) * ldkA + kq8;
    const u16* ga1 = ga0 + (size_t)16 * ldkA;
    const u16* gb0 = B + (size_t)(wave * 32 + r) * ldkB + kq8;
    const u16* gb1 = gb0 + (size_t)16 * ldkB;
    stage_chunk(ga0, ga1, gb0, gb1, 0, lAs, lBs, wave);
    __syncthreads();                           // chunk0 landed
    for (int kb = 0; kb < kChunks; ++kb) {
        if (kb + 1 < kChunks) {
            const int nx = ((kb + 1) & 1) * 4096;
            stage_chunk(ga0, ga1, gb0, gb1, kb + 1, lAs + nx, lBs + nx, wave);
        }
        const int cur = (kb & 1) * 4096;
        mfma_chunk(lAs + cur, lBs + cur, wave, lane, acc);
        __syncthreads();                       // drains prefetch AFTER compute
    }
}

// Shared GEMM-NT body (qkT and pv differ only in pointers/strides/scale).
__device__ inline void gemm_body(const u16* A, const u16* B, int ldk, int kChunks,
                                 u16* Cp, int ldc, float scale,
                                 int bx, int by, int tid, u16* lAs, u16* lBs)
{
    const int wave = tid >> 6, lane = tid & 63;
    f32x4 acc[4][4];
#pragma unroll
    for (int i = 0; i < 4; ++i)
#pragma unroll
        for (int j = 0; j < 4; ++j) acc[i][j] = (f32x4){0.f, 0.f, 0.f, 0.f};
    mfma_nt(A, ldk, B, ldk, kChunks, wave, lane, lAs, lBs, acc);
    const int wm = (wave >> 1) * 64, wn = (wave & 1) * 64;
    const int rb = (lane >> 4) * 4, cb = lane & 15;
#pragma unroll
    for (int i = 0; i < 4; ++i)
#pragma unroll
        for (int reg = 0; reg < 4; ++reg) {
            int gm = by * 128 + wm + i * 16 + rb + reg;
#pragma unroll
            for (int j = 0; j < 4; ++j) {
                int gn = bx * 128 + wn + j * 16 + cb;
                Cp[(size_t)gm * ldc + gn] = f2bf(acc[i][j][reg] * scale);
            }
        }
}

// ---------------------------------------------------------------------------
// r8 merged prep + xt (one launch). blocks [0,768) prep; [768,1792) xt.
// ---------------------------------------------------------------------------
__global__ __launch_bounds__(256) void k_px(const float* __restrict__ wq,
                                            const float* __restrict__ wk,
                                            const float* __restrict__ wv,
                                            const float* __restrict__ wo,
                                            u16* __restrict__ Wqkv, u16* __restrict__ WoT,
                                            const float* __restrict__ x,
                                            u16* __restrict__ Xt)
{
    __shared__ float ls[128 * 65];
    const int id = blockIdx.x;
    if (id < 768) {
        int idx = id * 256 + threadIdx.x;
        if (idx < 49152) {
            const float* w = idx < 16384 ? wq : (idx < 32768 ? wk : wv);
            Wqkv[idx] = f2bf(w[idx & 16383]);
        }
        int j = idx - 49152;
        if (j >= 0 && j < 147456) {
            int tap = j / 16384, rem = j % 16384;  // rem = cout*128+cin
            WoT[j] = f2bf(wo[(size_t)rem * 9 + tap]);
        }
        return;
    }
    const int b2 = id - 768;
    const int n = b2 >> 6, pix0 = (b2 & 63) * 64;
#pragma unroll
    for (int rep = 0; rep < 32; ++rep) {
        int idx = rep * 256 + threadIdx.x;
        int cin = idx >> 6, p = idx & 63;
        ls[cin * 65 + p] = x[((size_t)n * Dc + cin) * PIX + pix0 + p];
    }
    __syncthreads();
#pragma unroll
    for (int rep = 0; rep < 32; ++rep) {
        int idx = rep * 256 + threadIdx.x;
        int p = idx >> 7, cin = idx & 127;
        Xt[((size_t)n * PIX + pix0 + p) * Dc + cin] = f2bf(ls[cin * 65 + p]);
    }
}

// ---------------------------------------------------------------------------
// Fused QKV GEMM; Q/K scattered directly into patched layouts (both scales).
// grid (32 pixtiles, 3 mt, 16 imgs) = 1536 blocks.
// ---------------------------------------------------------------------------
__global__ __launch_bounds__(256) void k_qkv_mfma(const u16* __restrict__ Wqkv,
                                                  const u16* __restrict__ Xt,
                                                  const float* __restrict__ bq,
                                                  const float* __restrict__ bk,
                                                  const float* __restrict__ bv,
                                                  u16* __restrict__ Qp0, u16* __restrict__ Kp0,
                                                  u16* __restrict__ Qp1, u16* __restrict__ Kp1,
                                                  u16* __restrict__ v_bf)
{
    __shared__ u16 lAs[8192], lBs[8192];
    const int tid = threadIdx.x, wave = tid >> 6, lane = tid & 63;
    const int mt = blockIdx.y, n = blockIdx.z, px0 = blockIdx.x * 128;
    f32x4 acc[4][4];
#pragma unroll
    for (int i = 0; i < 4; ++i)
#pragma unroll
        for (int j = 0; j < 4; ++j) acc[i][j] = (f32x4){0.f, 0.f, 0.f, 0.f};
    mfma_nt(Wqkv + (size_t)mt * 128 * 128, 128,
            Xt + ((size_t)n * PIX + px0) * 128, 128, 4, wave, lane, lAs, lBs, acc);
    const int wm = (wave >> 1) * 64, wn = (wave & 1) * 64;
    const int rb = (lane >> 4) * 4, cb = lane & 15;
    const int bi = n >> 3, ti = n & 7;
    if (mt < 2) {
        const float* bp = (mt == 0) ? bq : bk;
        u16* d0 = (mt == 0) ? Qp0 : Kp0;
        u16* d1 = (mt == 0) ? Qp1 : Kp1;
#pragma unroll
        for (int i = 0; i < 4; ++i)
#pragma unroll
            for (int reg = 0; reg < 4; ++reg) {
                int c = wm + i * 16 + rb + reg;          // 0..127
                float bias = bp[c];
#pragma unroll
                for (int j = 0; j < 4; ++j) {
                    int pix = px0 + wn + j * 16 + cb;
                    int y = pix >> 6, x = pix & 63;
                    u16 val = f2bf(acc[i][j][reg] + bias);
                    if (c < 64) {                         // scale 0 (ps=4)
                        int l = ti * 256 + (y >> 2) * 16 + (x >> 2);
                        int f = c * 16 + (y & 3) * 4 + (x & 3);
                        d0[((size_t)bi * 2048 + l) * 1024 + f] = val;
                    } else {                              // scale 1 (ps=8)
                        int l = ti * 64 + (y >> 3) * 8 + (x >> 3);
                        int f = (c - 64) * 64 + (y & 7) * 8 + (x & 7);
                        d1[((size_t)bi * 512 + l) * 4096 + f] = val;
                    }
                }
            }
    } else {
#pragma unroll
        for (int i = 0; i < 4; ++i)
#pragma unroll
            for (int reg = 0; reg < 4; ++reg) {
                int c = wm + i * 16 + rb + reg;
                float bias = bv[c];
#pragma unroll
                for (int j = 0; j < 4; ++j) {
                    int pix = px0 + wn + j * 16 + cb;
                    v_bf[((size_t)n * Dc + c) * PIX + pix] = f2bf(acc[i][j][reg] + bias);
                }
            }
    }
}

// ---------------------------------------------------------------------------
// r10 FUSED k_vdw + k_depth. r7/r9 showed the fused kernel ran at the SERIAL
// sum because every block (incl. LDS-free depth blocks) paid the 24.5KB
// static LDS -> 6 blocks/CU, no slack for mem/VALU wave overlap. Fix: drop
// the 16KB x-staging array -- vdw now uses a rolling 3-row register window
// with wave shuffles for left/right neighbors (lane==x within each wave;
// OOB rows/cols contribute exact +-0, numerics unchanged). LDS = lv only
// (8.3KB) -> 8 blocks/CU; depth's VALU waves hide vdw's memory waves.
// ---------------------------------------------------------------------------
__global__ __launch_bounds__(256) void k_fuse(const float* __restrict__ X,
                                              const float* __restrict__ wvle,
                                              const float* __restrict__ bvle,
                                              const u16* __restrict__ v_bf,
                                              u16* __restrict__ Vt0,
                                              u16* __restrict__ Vt1,
                                              const float* __restrict__ dm,
                                              const float* __restrict__ wd1,
                                              const float* __restrict__ bd1,
                                              const float* __restrict__ wd2,
                                              float* __restrict__ part)
{
    __shared__ u16 lv[64 * 65];
    const int id = blockIdx.x;
    const int sub = id >> 1;
    const int tid = threadIdx.x;
    if ((id & 1) == 0) {
        // ---------------- vdw role (register rolling window, no x LDS) -----
        const int c = sub & 127, n = sub >> 7;
        const int bi = n >> 3, ti = n & 7;
        const float* xp = X + ((size_t)n * Dc + c) * PIX;
        float w[9];
#pragma unroll
        for (int t = 0; t < 9; ++t) w[t] = wvle[c * 9 + t];   // uniform -> s_load
        const float bias = bvle[c];
        const int x = tid & 63, y0 = (tid >> 6) * 16;
        const bool xl = (x > 0), xr = (x < 63);
        const u16* vp = v_bf + ((size_t)n * Dc + c) * PIX;
        // R[row][{l,c,r}] rolling window; neighbors via shuffles (lane == x).
        float R[3][3];
        auto ldrow = [&](int yy, float* dst) {
            float cc = (yy >= 0 && yy < 64) ? xp[yy * 64 + x] : 0.f; // wave-uniform cond
            float lu = __shfl_up(cc, 1);
            float rd = __shfl_down(cc, 1);
            dst[0] = xl ? lu : 0.f;
            dst[1] = cc;
            dst[2] = xr ? rd : 0.f;
        };
        ldrow(y0 - 1, R[0]);
        ldrow(y0,     R[1]);
#pragma unroll
        for (int r = 0; r < 16; ++r) {
            const int y = y0 + r;
            ldrow(y + 1, R[2]);
            float s = bias;
            s += w[0] * R[0][0] + w[1] * R[0][1] + w[2] * R[0][2];
            s += w[3] * R[1][0] + w[4] * R[1][1] + w[5] * R[1][2];
            s += w[6] * R[2][0] + w[7] * R[2][1] + w[8] * R[2][2];
            lv[y * 65 + x] = f2bf(bf2f(vp[y * 64 + x]) + s);
            R[0][0] = R[1][0]; R[0][1] = R[1][1]; R[0][2] = R[1][2];
            R[1][0] = R[2][0]; R[1][1] = R[2][1]; R[1][2] = R[2][2];
        }
        __syncthreads();
        if (c < 64) {                             // scale 0: ps=4, F=1024, L=2048
            const int fsub = tid >> 4;            // = (y&3)*4 + (x&3)
            const int py = fsub >> 2, px = fsub & 3;
            const int oh = tid & 15;
            u16 buf[16];
#pragma unroll
            for (int ow = 0; ow < 16; ++ow)
                buf[ow] = lv[(oh * 4 + py) * 65 + ow * 4 + px];
            size_t dst = ((size_t)bi * 1024 + (c * 16 + fsub)) * 2048 + ti * 256 + oh * 16;
            *(uint4*)&Vt0[dst]     = *(const uint4*)&buf[0];
            *(uint4*)&Vt0[dst + 8] = *(const uint4*)&buf[8];
        } else {                                  // scale 1: ps=8, F=4096, L=512
            const int fsub = tid >> 2;            // = (y&7)*8 + (x&7)
            const int py = fsub >> 3, px = fsub & 7;
            const int l0 = (tid & 3) * 16;
            u16 buf[16];
#pragma unroll
            for (int e = 0; e < 16; ++e) {
                int l = l0 + e, oh = l >> 3, ow = l & 7;
                buf[e] = lv[(oh * 8 + py) * 65 + ow * 8 + px];
            }
            size_t dst = ((size_t)bi * 4096 + ((c - 64) * 64 + fsub)) * 512 + ti * 64 + l0;
            *(uint4*)&Vt1[dst]     = *(const uint4*)&buf[0];
            *(uint4*)&Vt1[dst + 8] = *(const uint4*)&buf[8];
        }
    } else {
        // ---------------- depth role (r5 band version, 8-way split) --------
        const int tile = sub & 15, n = (sub >> 4) & 15, cs = sub >> 8;
        const int ty = tid >> 4, tx = tid & 15;
        const int y = (tile >> 2) * 16 + ty;
        const int x = (tile & 3) * 16 + tx;
        const float* dmp = dm + (size_t)n * 65536;
        const int gc0 = 4 * x - 4;
        const bool vy = (y > 0), vx = (x > 0);
        const int c0 = cs * 16;
        float acc = 0.f;
#pragma unroll 1
        for (int jy = 0; jy < 3; ++jy) {
            // rw[rr][i] = dm[4y-3+2jy+rr][4x-3+i], i=0..6, zero-padded.
            float rw[3][7];
#pragma unroll
            for (int rr = 0; rr < 3; ++rr) {
                const int gr = 4 * y - 3 + 2 * jy + rr;
                const float* rp = dmp + gr * 256 + gc0;
                const bool rok = (gr >= 0);
                float4 va = (rok && x > 0) ? *(const float4*)rp
                                           : make_float4(0.f, 0.f, 0.f, 0.f);
                float4 vb = rok ? *(const float4*)(rp + 4)
                                : make_float4(0.f, 0.f, 0.f, 0.f);
                rw[rr][0] = va.y; rw[rr][1] = va.z; rw[rr][2] = va.w;
                rw[rr][3] = vb.x; rw[rr][4] = vb.y; rw[rr][5] = vb.z; rw[rr][6] = vb.w;
            }
            // pin the 21-float band (small set: benign, r2/r5 verified)
#pragma unroll
            for (int rr = 0; rr < 3; ++rr)
#pragma unroll
                for (int i = 0; i < 7; ++i) asm volatile("" : "+v"(rw[rr][i]));
            const bool oky = (jy > 0) || vy;
#pragma unroll 2
            for (int cc = 0; cc < 16; ++cc) {
                const int c = c0 + cc;
                const float* w1 = wd1 + c * 9;            // uniform -> s_load
                const float* w2 = wd2 + c * 9 + jy * 3;   // uniform -> s_load
                const float b1 = bd1[c];
#pragma unroll
                for (int jx = 0; jx < 3; ++jx) {
                    float s = b1;
#pragma unroll
                    for (int ky = 0; ky < 3; ++ky)
#pragma unroll
                        for (int kx = 0; kx < 3; ++kx)
                            s += w1[ky * 3 + kx] * rw[ky][2 * jx + kx];
                    s = fmaxf(s, 0.f);
                    const bool ok = oky && ((jx > 0) || vx);
                    acc += w2[jx] * (ok ? s : 0.f);
                }
            }
        }
        part[((size_t)cs * 16 + n) * PIX + y * 64 + x] = acc;
    }
}

// Depth path finalize: dep = relu(sum of 8 channel-split partials + bd2).
__global__ void k_dfin(const float* __restrict__ part, const float* __restrict__ bd2,
                       float* __restrict__ dep)
{
    int idx = blockIdx.x * 256 + threadIdx.x;
    float s = bd2[0];
#pragma unroll
    for (int cg = 0; cg < 8; ++cg) s += part[(size_t)cg * 65536 + idx];
    dep[idx] = fmaxf(s, 0.f);
}

// ---------------------------------------------------------------------------
// Wave-parallel per-token stats; r8: both scales merged into one launch.
// ---------------------------------------------------------------------------
template<int PS>
__device__ inline void stats_body(int sid, const float* __restrict__ mI,
                                  const float* __restrict__ dep,
                                  float* __restrict__ maskf, float* __restrict__ smed,
                                  float* __restrict__ smaxA, float* __restrict__ sminA,
                                  int outn, int L)
{
    constexpr int HW = PS * PS;              // 16 or 64
    constexpr int TPB = 256 / HW;
    const int tok = sid * TPB + (int)threadIdx.x / HW;
    const int el  = threadIdx.x % HW;
    if (tok >= Bb * L) return;
    const int bi = tok / L, l = tok % L;
    const int ti = l / (outn * outn); const int rem = l % (outn * outn);
    const int oh = rem / outn, ow = rem % outn;
    const int n = bi * Tt + ti;
    const int py = el / PS, px = el % PS;
    const size_t off = (size_t)n * PIX + (size_t)(oh * PS + py) * 64 + ow * PS + px;
    const float mv = mI[off];
    const float dv = dep[off];
    float msum = mv, vmin = dv, vmax = dv;
#pragma unroll
    for (int o = HW / 2; o > 0; o >>= 1) {
        msum += __shfl_xor(msum, o);
        vmin = fminf(vmin, __shfl_xor(vmin, o));
        vmax = fmaxf(vmax, __shfl_xor(vmax, o));
    }
    const int gbase = (threadIdx.x & 63) & ~(HW - 1);
    int cl = 0, ce = 0;
#pragma unroll
    for (int b2 = 0; b2 < HW; ++b2) {
        float vb = __shfl(dv, gbase + b2);
        cl += (vb < dv);
        ce += (vb == dv);
    }
    constexpr int kk = (HW - 1) / 2;
    if (el == 0) {
        maskf[tok] = (msum / (float)HW > 0.5f) ? 1.f : 0.f;
        smaxA[tok] = 1.f / (1.f + __expf(-vmax));
        sminA[tok] = 1.f / (1.f + __expf(-vmin));
    }
    if (cl <= kk && kk < cl + ce)
        smed[tok] = 1.f / (1.f + __expf(-dv));
}

__global__ __launch_bounds__(256) void k_stats(const float* __restrict__ mI,
                                               const float* __restrict__ dep,
                                               float* __restrict__ mk0, float* __restrict__ s00,
                                               float* __restrict__ s10, float* __restrict__ s20,
                                               float* __restrict__ mk1, float* __restrict__ s01,
                                               float* __restrict__ s11, float* __restrict__ s21)
{
    const int id = blockIdx.x;
    if (id < 256) stats_body<4>(id, mI, dep, mk0, s00, s10, s20, 16, 2048);
    else          stats_body<8>(id - 256, mI, dep, mk1, s01, s11, s21, 8, 512);
}

// ---------------------------------------------------------------------------
// r8 merged qkT (both scales, one launch).
// scale0: L=2048 F=1024 ksplit=2 kf=512 -> 16x16x4 = 1024 blocks
// scale1: L= 512 F=4096 ksplit=16 kf=256 -> 4x4x32  =  512 blocks
// ---------------------------------------------------------------------------
__global__ __launch_bounds__(256) void k_qkT2(const u16* __restrict__ Qp0,
                                              const u16* __restrict__ Kp0,
                                              u16* __restrict__ Sb0,
                                              const u16* __restrict__ Qp1,
                                              const u16* __restrict__ Kp1,
                                              u16* __restrict__ Sb1)
{
    __shared__ u16 lAs[8192], lBs[8192];
    int id = blockIdx.x;
    const int tid = threadIdx.x;
    if (id < 1024) {
        const int bx = id & 15, by = (id >> 4) & 15, z = id >> 8;  // z 0..3
        const int bi = z >> 1, ks = z & 1;
        const u16* A = Qp0 + (size_t)bi * 2048 * 1024 + (size_t)by * 128 * 1024 + (size_t)ks * 512;
        const u16* B = Kp0 + (size_t)bi * 2048 * 1024 + (size_t)bx * 128 * 1024 + (size_t)ks * 512;
        u16* Cp = Sb0 + ((size_t)ks * Bb + bi) * 2048 * 2048;
        gemm_body(A, B, 1024, 16, Cp, 2048, 0.03125f, bx, by, tid, lAs, lBs);
    } else {
        id -= 1024;
        const int bx = id & 3, by = (id >> 2) & 3, z = id >> 4;    // z 0..31
        const int bi = z >> 4, ks = z & 15;
        const u16* A = Qp1 + (size_t)bi * 512 * 4096 + (size_t)by * 128 * 4096 + (size_t)ks * 256;
        const u16* B = Kp1 + (size_t)bi * 512 * 4096 + (size_t)bx * 128 * 4096 + (size_t)ks * 256;
        u16* Cp = Sb1 + ((size_t)ks * Bb + bi) * 512 * 512;
        gemm_body(A, B, 4096, 8, Cp, 512, 0.015625f, bx, by, tid, lAs, lBs);
    }
}

// ---------------------------------------------------------------------------
// 3-head softmax body (coalesced adjacent-pair mapping); r8 merged launch.
// ---------------------------------------------------------------------------
__device__ inline float blockMax(float v, float* sh) {
#pragma unroll
    for (int o = 32; o > 0; o >>= 1) v = fmaxf(v, __shfl_down(v, o));
    __syncthreads();
    if ((threadIdx.x & 63) == 0) sh[threadIdx.x >> 6] = v;
    __syncthreads();
    return fmaxf(fmaxf(sh[0], sh[1]), fmaxf(sh[2], sh[3]));
}
__device__ inline float blockSum(float v, float* sh) {
#pragma unroll
    for (int o = 32; o > 0; o >>= 1) v += __shfl_down(v, o);
    __syncthreads();
    if ((threadIdx.x & 63) == 0) sh[threadIdx.x >> 6] = v;
    __syncthreads();
    return sh[0] + sh[1] + sh[2] + sh[3];
}

template<int NPAIR, int NSPLIT>
__device__ inline void softmax_body(const u16* __restrict__ S, u16* __restrict__ Pb,
                                    const float* __restrict__ maskf,
                                    const float* __restrict__ smed,
                                    const float* __restrict__ smaxA,
                                    const float* __restrict__ sminA,
                                    int L, int bi, int q, float* sred)
{
    const size_t pstr = (size_t)Bb * L * L;
    const u16* row = S + (size_t)bi * L * L + (size_t)q * L;
    u16* prow = Pb + (size_t)bi * L * L + (size_t)q * L;
    const float* mk  = maskf + bi * L;
    const float* s0p = smed  + bi * L;
    const float* s1p = smaxA + bi * L;
    const float* s2p = sminA + bi * L;
    const int tid = threadIdx.x;
    float a0[2 * NPAIR], a1[2 * NPAIR], a2[2 * NPAIR];
    float m0 = -3.4e38f, m1 = -3.4e38f, m2 = -3.4e38f;
#pragma unroll
    for (int e = 0; e < NPAIR; ++e) {
        int k = e * 512 + tid * 2;
        unsigned u = *(const unsigned*)&row[k];
        float sva = bf2f((u16)(u & 0xffffu));
        float svb = bf2f((u16)(u >> 16));
#pragma unroll
        for (int s2 = 1; s2 < NSPLIT; ++s2) {
            unsigned w = *(const unsigned*)&row[(size_t)s2 * pstr + k];
            sva += bf2f((u16)(w & 0xffffu));
            svb += bf2f((u16)(w >> 16));
        }
        float2 mv  = *(const float2*)&mk[k];
        float2 p0  = *(const float2*)&s0p[k];
        float2 p1  = *(const float2*)&s1p[k];
        float2 p2  = *(const float2*)&s2p[k];
        bool ma = mv.x > 0.5f, mb = mv.y > 0.5f;
        float v0a = ma ? -1e9f : sva * p0.x, v0b = mb ? -1e9f : svb * p0.y;
        float v1a = ma ? -1e9f : sva * p1.x, v1b = mb ? -1e9f : svb * p1.y;
        float v2a = ma ? -1e9f : sva * p2.x, v2b = mb ? -1e9f : svb * p2.y;
        a0[2 * e] = v0a; a0[2 * e + 1] = v0b;
        a1[2 * e] = v1a; a1[2 * e + 1] = v1b;
        a2[2 * e] = v2a; a2[2 * e + 1] = v2b;
        m0 = fmaxf(m0, fmaxf(v0a, v0b));
        m1 = fmaxf(m1, fmaxf(v1a, v1b));
        m2 = fmaxf(m2, fmaxf(v2a, v2b));
    }
    m0 = blockMax(m0, sred); m1 = blockMax(m1, sred); m2 = blockMax(m2, sred);
    float l0 = 0.f, l1 = 0.f, l2 = 0.f;
#pragma unroll
    for (int e = 0; e < 2 * NPAIR; ++e) {
        a0[e] = __expf(a0[e] - m0); l0 += a0[e];
        a1[e] = __expf(a1[e] - m1); l1 += a1[e];
        a2[e] = __expf(a2[e] - m2); l2 += a2[e];
    }
    l0 = blockSum(l0, sred); l1 = blockSum(l1, sred); l2 = blockSum(l2, sred);
    float c0 = 1.f / (3.f * l0), c1 = 1.f / (3.f * l1), c2 = 1.f / (3.f * l2);
#pragma unroll
    for (int e = 0; e < NPAIR; ++e) {
        int k = e * 512 + tid * 2;
        u16 oa = f2bf(a0[2 * e] * c0 + a1[2 * e] * c1 + a2[2 * e] * c2);
        u16 ob = f2bf(a0[2 * e + 1] * c0 + a1[2 * e + 1] * c1 + a2[2 * e + 1] * c2);
        unsigned pk = (unsigned)oa | ((unsigned)ob << 16);
        *(unsigned*)&prow[k] = pk;
    }
}

__global__ __launch_bounds__(256) void k_sm2(const u16* __restrict__ Sb0, u16* __restrict__ Pb0,
                                             const float* __restrict__ mk0, const float* __restrict__ s00,
                                             const float* __restrict__ s10, const float* __restrict__ s20,
                                             const u16* __restrict__ Sb1, u16* __restrict__ Pb1,
                                             const float* __restrict__ mk1, const float* __restrict__ s01,
                                             const float* __restrict__ s11, const float* __restrict__ s21)
{
    __shared__ float sred[4];
    int id = blockIdx.x;
    if (id < 4096) {
        const int bi = id >> 11, q = id & 2047;
        softmax_body<4, 2>(Sb0, Pb0, mk0, s00, s10, s20, 2048, bi, q, sred);
    } else {
        id -= 4096;
        const int bi = id >> 9, q = id & 511;
        softmax_body<1, 16>(Sb1, Pb1, mk1, s01, s11, s21, 512, bi, q, sred);
    }
}

// ---------------------------------------------------------------------------
// r8 merged PV (both scales, one launch). pvsplit=2 both (halved Yp traffic).
// scale0: L=2048 F=1024 kf=1024 -> 8x16x4 = 512 blocks (32 chunks)
// scale1: L= 512 F=4096 kf= 256 -> 32x4x4 = 512 blocks (8 chunks)
// ---------------------------------------------------------------------------
__global__ __launch_bounds__(256) void k_pv2(const u16* __restrict__ Pb0,
                                             const u16* __restrict__ Vt0,
                                             u16* __restrict__ Yp0,
                                             const u16* __restrict__ Pb1,
                                             const u16* __restrict__ Vt1,
                                             u16* __restrict__ Yp1)
{
    __shared__ u16 lAs[8192], lBs[8192];
    int id = blockIdx.x;
    const int tid = threadIdx.x;
    if (id < 512) {
        const int bx = id & 7, by = (id >> 3) & 15, z = id >> 7;   // z 0..3
        const int bi = z >> 1, ks = z & 1;
        const u16* A = Pb0 + (size_t)bi * 2048 * 2048 + (size_t)by * 128 * 2048 + (size_t)ks * 1024;
        const u16* B = Vt0 + (size_t)bi * 1024 * 2048 + (size_t)bx * 128 * 2048 + (size_t)ks * 1024;
        u16* Cp = Yp0 + ((size_t)ks * Bb + bi) * 2048 * 1024;
        gemm_body(A, B, 2048, 32, Cp, 1024, 1.0f, bx, by, tid, lAs, lBs);
    } else {
        id -= 512;
        const int bx = id & 31, by = (id >> 5) & 3, z = id >> 7;   // z 0..3
        const int bi = z >> 1, ks = z & 1;
        const u16* A = Pb1 + (size_t)bi * 512 * 512 + (size_t)by * 128 * 512 + (size_t)ks * 256;
        const u16* B = Vt1 + (size_t)bi * 4096 * 512 + (size_t)bx * 128 * 512 + (size_t)ks * 256;
        u16* Cp = Yp1 + ((size_t)ks * Bb + bi) * 512 * 4096;
        gemm_body(A, B, 512, 8, Cp, 4096, 1.0f, bx, by, tid, lAs, lBs);
    }
}

// ---------------------------------------------------------------------------
// r8 merged unpatch (NSPLIT=2 now). 4096 blocks per scale.
// ---------------------------------------------------------------------------
template<int NSPLIT>
__device__ inline void unp_body(int sid, const u16* __restrict__ Yp, u16* __restrict__ catbT,
                                int ps, int outn, int L, int F, int cbase)
{
    size_t idx = (size_t)sid * 256 + threadIdx.x;
    size_t total = (size_t)Bb * L * F / 4;
    if (idx >= total) return;
    const size_t pstr = (size_t)Bb * L * F;
    int f0 = (int)((idx * 4) % F);
    size_t t2 = (idx * 4) / F;
    int l = (int)(t2 % L);
    int bi = (int)(t2 / L);
    size_t off = ((size_t)bi * L + l) * F + f0;
    float s[4] = {0.f, 0.f, 0.f, 0.f};
#pragma unroll
    for (int sp = 0; sp < NSPLIT; ++sp) {
        uint2 u = *(const uint2*)&Yp[(size_t)sp * pstr + off];
        s[0] += bf2f((u16)(u.x & 0xffffu));
        s[1] += bf2f((u16)(u.x >> 16));
        s[2] += bf2f((u16)(u.y & 0xffffu));
        s[3] += bf2f((u16)(u.y >> 16));
    }
    int hw = ps * ps;
    int c = cbase + f0 / hw, r0 = f0 % hw;
    int ti = l / (outn * outn); int rem = l % (outn * outn);
    int oh = rem / outn, ow = rem % outn;
    int n = bi * Tt + ti;
    int py = r0 / ps, px = r0 % ps;   // r0 4-aligned -> same row, 4 consecutive px
    size_t base = ((size_t)n * PIX + (size_t)(oh * ps + py) * 64 + ow * ps + px) * Dc + c;
#pragma unroll
    for (int e = 0; e < 4; ++e)
        catbT[base + (size_t)e * Dc] = f2bf(s[e]);
}

__global__ void k_unp2(const u16* __restrict__ Yp0, const u16* __restrict__ Yp1,
                       u16* __restrict__ catbT)
{
    const int id = blockIdx.x;
    if (id < 4096) unp_body<2>(id, Yp0, catbT, 4, 16, 2048, 1024, 0);
    else           unp_body<2>(id - 4096, Yp1, catbT, 8, 8, 512, 4096, 64);
}

// ---------------------------------------------------------------------------
// Output conv 3x3 as implicit NT GEMM over catbT, tap-split 2-way,
// prefetch-pipelined. grid (512, 2) = 1024 blocks. bf16 [pix][cout] partials.
// ---------------------------------------------------------------------------
__global__ __launch_bounds__(256) void k_conv_mfma(const u16* __restrict__ catbT,
                                                   const u16* __restrict__ WoT,
                                                   const u16* __restrict__ zp,
                                                   u16* __restrict__ Cpart)
{
    __shared__ u16 lAs[8192], lBs[8192];
    const int tid = threadIdx.x, wave = tid >> 6, lane = tid & 63;
    const int pix0 = blockIdx.x * 128;
    const int sp = blockIdx.y;
    const int r = lane >> 2;
    const int kq8 = ((lane & 3) ^ ((r >> 1) & 3)) * 8;   // swizzled source seg
    int yb[2], xb[2], nn[2];
#pragma unroll
    for (int s = 0; s < 2; ++s) {
        int pg = pix0 + wave * 32 + r + s * 16;
        nn[s] = pg >> 12; yb[s] = (pg >> 6) & 63; xb[s] = pg & 63;
    }
    const u16* gb_base = WoT + (size_t)(wave * 32 + r) * 128 + kq8;

    auto stage = [&](int tt, int hb) {
        const int t = sp * 18 + tt;
        const int tap = t >> 2, kc = t & 3;
        const int dy = tap / 3 - 1, dx = tap % 3 - 1;
        const u16* ga[2];
#pragma unroll
        for (int s = 0; s < 2; ++s) {
            int y = yb[s] + dy, xx = xb[s] + dx;
            bool ok = ((unsigned)y < 64u) && ((unsigned)xx < 64u);
            ga[s] = ok ? catbT + (((size_t)(nn[s] << 12) + y * 64 + xx) << 7) + kq8 + kc * 32 : zp;
        }
        const u16* gb = gb_base + tap * 16384 + kc * 32;
        GLOAD16(ga[0],     lAs + hb * 4096 + wave * 1024);
        GLOAD16(ga[1],     lAs + hb * 4096 + wave * 1024 + 512);
        GLOAD16(gb,        lBs + hb * 4096 + wave * 1024);
        GLOAD16(gb + 2048, lBs + hb * 4096 + wave * 1024 + 512);
    };

    f32x4 acc[4][4];
#pragma unroll
    for (int i = 0; i < 4; ++i)
#pragma unroll
        for (int j = 0; j < 4; ++j) acc[i][j] = (f32x4){0.f, 0.f, 0.f, 0.f};

    stage(0, 0);
    __syncthreads();
    for (int tt = 0; tt < 18; ++tt) {
        if (tt + 1 < 18) stage(tt + 1, (tt + 1) & 1);
        const int cur = (tt & 1) * 4096;
        mfma_chunk(lAs + cur, lBs + cur, wave, lane, acc);
        __syncthreads();
    }

    const int wm = (wave >> 1) * 64, wn = (wave & 1) * 64;
    const int rb = (lane >> 4) * 4, cb = lane & 15;
    u16* Cp = Cpart + (size_t)sp * 8388608;
#pragma unroll
    for (int i = 0; i < 4; ++i)
#pragma unroll
        for (int reg = 0; reg < 4; ++reg) {
            int gm = pix0 + wm + i * 16 + rb + reg;          // global pixel
#pragma unroll
            for (int j = 0; j < 4; ++j) {
                int gn = wn + j * 16 + cb;                   // cout
                Cp[(size_t)gm * 128 + gn] = f2bf(acc[i][j][reg]);
            }
        }
}

// ---------------------------------------------------------------------------
// Conv finalize: out = leaky(sum of 2 bf16 partials + bias), NCHW fp32.
// ---------------------------------------------------------------------------
__global__ __launch_bounds__(256) void k_cfin(const u16* __restrict__ Cpart,
                                              const float* __restrict__ bo,
                                              float* __restrict__ outp)
{
    const int pg0 = blockIdx.x * 64;
    const int lane = threadIdx.x & 63, wv = threadIdx.x >> 6;
    const int pix = pg0 + lane;
    const int n = pix >> 12, p = pix & 4095;
    const u16* r0 = Cpart + (size_t)pix * 128 + wv * 32;
    const u16* r1 = r0 + 8388608;
#pragma unroll
    for (int c4 = 0; c4 < 8; ++c4) {
        uint2 a = *(const uint2*)(r0 + c4 * 4);
        uint2 b = *(const uint2*)(r1 + c4 * 4);
        float s[4];
        s[0] = bf2f((u16)(a.x & 0xffffu)) + bf2f((u16)(b.x & 0xffffu));
        s[1] = bf2f((u16)(a.x >> 16))     + bf2f((u16)(b.x >> 16));
        s[2] = bf2f((u16)(a.y & 0xffffu)) + bf2f((u16)(b.y & 0xffffu));
        s[3] = bf2f((u16)(a.y >> 16))     + bf2f((u16)(b.y >> 16));
#pragma unroll
        for (int e = 0; e < 4; ++e) {
            int cout = wv * 32 + c4 * 4 + e;
            float v = s[e] + bo[cout];
            v = (v >= 0.f) ? v : 0.2f * v;
            outp[((size_t)n * Dc + cout) * PIX + p] = v;
        }
    }
}

// ---------------------------------------------------------------------------
extern "C" void kernel_launch(void* const* d_in, const int* in_sizes, int n_in,
                              void* d_out, int out_size, void* d_ws, size_t ws_size,
                              hipStream_t stream)
{
    (void)in_sizes; (void)n_in; (void)out_size; (void)ws_size;
    const float* x    = (const float*)d_in[0];
    const float* mI   = (const float*)d_in[1];
    const float* dmap = (const float*)d_in[2];
    const float* wq   = (const float*)d_in[3];
    const float* bq   = (const float*)d_in[4];
    const float* wk   = (const float*)d_in[5];
    const float* bk   = (const float*)d_in[6];
    const float* wv   = (const float*)d_in[7];
    const float* bv   = (const float*)d_in[8];
    const float* wvle = (const float*)d_in[9];
    const float* bvle = (const float*)d_in[10];
    const float* wd1  = (const float*)d_in[11];
    const float* bd1  = (const float*)d_in[12];
    const float* wd2  = (const float*)d_in[13];
    const float* bd2  = (const float*)d_in[14];
    const float* wo   = (const float*)d_in[15];
    const float* bo   = (const float*)d_in[16];

    // workspace layout (~164 MB). Aliases (timeline-checked):
    //   Yp0 @ 0x0     (16MB): over v_bf (dead after k_fuse); pv2 later
    //   Yp1 @ Sb0     (16MB): Sb0 dead after k_sm2; pv2 later
    //   Cpart @ Sb0   (32MB): conv runs after unp2 (Yp1 dead by then)
    char* w8 = (char*)d_ws;
    u16*   v_bf  = (u16*)(w8);                    // 16 MB [w:qkv r:fuse]
    u16*   Xt    = (u16*)(w8 + 0x1000000);        // 16 MB [w:px r:qkv]
    u16*   Yp0   = (u16*)(w8);                    // 16 MB [w:pv2 r:unp2] alias
    u16*   catbT = (u16*)(w8 + 0x2000000);        // 16 MB [w:unp2 r:conv]
    u16*   Qp0   = (u16*)(w8 + 0x3000000);        // 8 MB
    u16*   Kp0   = (u16*)(w8 + 0x3800000);
    u16*   Qp1   = (u16*)(w8 + 0x4000000);
    u16*   Kp1   = (u16*)(w8 + 0x4800000);
    u16*   Vt0   = (u16*)(w8 + 0x5000000);        // 8 MB
    u16*   Vt1   = (u16*)(w8 + 0x5800000);        // 8 MB
    u16*   Sb0   = (u16*)(w8 + 0x6000000);        // 32 MB [w:qkT2 r:sm2]
    u16*   Yp1   = (u16*)(w8 + 0x6000000);        // 16 MB [w:pv2 r:unp2] alias
    u16*   Cpart = (u16*)(w8 + 0x6000000);        // 32 MB [w:conv r:cfin] alias
    u16*   Sb1   = (u16*)(w8 + 0x8000000);        // 16 MB [w:qkT2 r:sm2]
    u16*   Pb0   = (u16*)(w8 + 0x9000000);        // 16 MB [w:sm2 r:pv2]
    u16*   Pb1   = (u16*)(w8 + 0xA000000);        // 1 MB  [w:sm2 r:pv2]
    float* part  = (float*)(w8 + 0xA100000);      // 2 MB
    float* dep   = (float*)(w8 + 0xA300000);      // 256 KB
    float* maskf = (float*)(w8 + 0xA340000);
    float* smed  = (float*)(w8 + 0xA344000);
    float* smaxA = (float*)(w8 + 0xA348000);
    float* sminA = (float*)(w8 + 0xA34C000);
    float* mk1   = (float*)(w8 + 0xA350000);
    float* sm1a  = (float*)(w8 + 0xA354000);
    float* sm1b  = (float*)(w8 + 0xA358000);
    float* sm1c  = (float*)(w8 + 0xA35C000);
    u16*   Wqkv  = (u16*)(w8 + 0xA360000);        // 96 KB
    u16*   WoT   = (u16*)(w8 + 0xA378000);        // 288 KB
    u16*   zp    = (u16*)(w8 + 0xA3C0000);
    float* outp  = (float*)d_out;

    hipMemcpyAsync(outp + 8388608, dmap, (size_t)16 * 65536 * sizeof(float),
                   hipMemcpyDeviceToDevice, stream);
    hipMemsetAsync(zp, 0, 256, stream);

    dim3 blk(256);
    k_px<<<dim3(1792), blk, 0, stream>>>(wq, wk, wv, wo, Wqkv, WoT, x, Xt);
    k_qkv_mfma<<<dim3(32, 3, 16), blk, 0, stream>>>(Wqkv, Xt, bq, bk, bv,
                                                    Qp0, Kp0, Qp1, Kp1, v_bf);

    // fused vdw + depth (LDS-light vdw for true co-residency)
    k_fuse<<<dim3(4096), blk, 0, stream>>>(x, wvle, bvle, v_bf, Vt0, Vt1,
                                           dmap, wd1, bd1, wd2, part);
    k_dfin<<<dim3(256), blk, 0, stream>>>(part, bd2, dep);

    // merged attention pipeline (both scales per launch)
    k_stats<<<dim3(512), blk, 0, stream>>>(mI, dep, maskf, smed, smaxA, sminA,
                                           mk1, sm1a, sm1b, sm1c);
    k_qkT2<<<dim3(1536), blk, 0, stream>>>(Qp0, Kp0, Sb0, Qp1, Kp1, Sb1);
    k_sm2<<<dim3(5120), blk, 0, stream>>>(Sb0, Pb0, maskf, smed, smaxA, sminA,
                                          Sb1, Pb1, mk1, sm1a, sm1b, sm1c);
    k_pv2<<<dim3(1024), blk, 0, stream>>>(Pb0, Vt0, Yp0, Pb1, Vt1, Yp1);
    k_unp2<<<dim3(8192), blk, 0, stream>>>(Yp0, Yp1, catbT);

    k_conv_mfma<<<dim3(512, 2), blk, 0, stream>>>(catbT, WoT, zp, Cpart);
    k_cfin<<<dim3(1024), blk, 0, stream>>>(Cpart, bo, outp);
}

// Round 11
// 381.537 us; speedup vs baseline: 1.0187x; 1.0187x over previous
//
#include <hip/hip_runtime.h>
#include <cmath>

typedef unsigned short u16;
typedef __attribute__((ext_vector_type(8))) __bf16 bf16x8;
typedef __attribute__((ext_vector_type(4))) float f32x4;

constexpr int Bb = 2, Tt = 8, Dc = 128, PIX = 4096; // b=2, c=128, 64x64 imgs

__device__ inline u16 f2bf(float f) {
    unsigned u = __builtin_bit_cast(unsigned, f);
    u += 0x7fffu + ((u >> 16) & 1u);
    return (u16)(u >> 16);
}
__device__ inline float bf2f(u16 h) {
    unsigned u = ((unsigned)h) << 16;
    return __builtin_bit_cast(float, u);
}

#define GLOAD16(gp, lp) __builtin_amdgcn_global_load_lds( \
    (const __attribute__((address_space(1))) void*)(const void*)(gp), \
    (__attribute__((address_space(3))) void*)(void*)(lp), 16, 0, 0)

// ---------------------------------------------------------------------------
// bf16 NT MFMA core, 2-phase prefetch pipeline (r4).
// ---------------------------------------------------------------------------
__device__ inline void mfma_chunk(const u16* lAs, const u16* lBs, int wave, int lane,
                                  f32x4 (&acc)[4][4])
{
    const int wm = (wave >> 1) * 64, wn = (wave & 1) * 64;
    const int fr = lane & 15;
    const int q4 = lane >> 4;                         // wanted global k-quarter
    const int sw = (q4 ^ ((fr >> 1) & 3)) * 8;        // swizzled storage seg
    bf16x8 av[4], bv[4];
#pragma unroll
    for (int i = 0; i < 4; ++i) av[i] = *(const bf16x8*)&lAs[(wm + i * 16 + fr) * 32 + sw];
#pragma unroll
    for (int j = 0; j < 4; ++j) bv[j] = *(const bf16x8*)&lBs[(wn + j * 16 + fr) * 32 + sw];
#pragma unroll
    for (int i = 0; i < 4; ++i)
#pragma unroll
        for (int j = 0; j < 4; ++j)
            acc[i][j] = __builtin_amdgcn_mfma_f32_16x16x32_bf16(av[i], bv[j], acc[i][j], 0, 0, 0);
}

__device__ inline void stage_chunk(const u16* ga0, const u16* ga1,
                                   const u16* gb0, const u16* gb1,
                                   int kb, u16* lA, u16* lB, int wave)
{
    GLOAD16(ga0 + kb * 32, lA + wave * 1024);
    GLOAD16(ga1 + kb * 32, lA + wave * 1024 + 512);
    GLOAD16(gb0 + kb * 32, lB + wave * 1024);
    GLOAD16(gb1 + kb * 32, lB + wave * 1024 + 512);
}

// kChunks = number of 32-K chunks (any count >= 1).
__device__ inline void mfma_nt(const u16* A, int ldkA, const u16* B, int ldkB,
                               int kChunks, int wave, int lane,
                               u16* lAs, u16* lBs, f32x4 (&acc)[4][4])
{
    const int r = lane >> 2;                              // row within 16-group
    const int kq8 = ((lane & 3) ^ ((r >> 1) & 3)) * 8;    // swizzled source seg
    const u16* ga0 = A + (size_t)(wave * 32 + r) * ldkA + kq8;
    const u16* ga1 = ga0 + (size_t)16 * ldkA;
    const u16* gb0 = B + (size_t)(wave * 32 + r) * ldkB + kq8;
    const u16* gb1 = gb0 + (size_t)16 * ldkB;
    stage_chunk(ga0, ga1, gb0, gb1, 0, lAs, lBs, wave);
    __syncthreads();                           // chunk0 landed
    for (int kb = 0; kb < kChunks; ++kb) {
        if (kb + 1 < kChunks) {
            const int nx = ((kb + 1) & 1) * 4096;
            stage_chunk(ga0, ga1, gb0, gb1, kb + 1, lAs + nx, lBs + nx, wave);
        }
        const int cur = (kb & 1) * 4096;
        mfma_chunk(lAs + cur, lBs + cur, wave, lane, acc);
        __syncthreads();                       // drains prefetch AFTER compute
    }
}

// Shared GEMM-NT body (qkT and pv differ only in pointers/strides/scale).
__device__ inline void gemm_body(const u16* A, const u16* B, int ldk, int kChunks,
                                 u16* Cp, int ldc, float scale,
                                 int bx, int by, int tid, u16* lAs, u16* lBs)
{
    const int wave = tid >> 6, lane = tid & 63;
    f32x4 acc[4][4];
#pragma unroll
    for (int i = 0; i < 4; ++i)
#pragma unroll
        for (int j = 0; j < 4; ++j) acc[i][j] = (f32x4){0.f, 0.f, 0.f, 0.f};
    mfma_nt(A, ldk, B, ldk, kChunks, wave, lane, lAs, lBs, acc);
    const int wm = (wave >> 1) * 64, wn = (wave & 1) * 64;
    const int rb = (lane >> 4) * 4, cb = lane & 15;
#pragma unroll
    for (int i = 0; i < 4; ++i)
#pragma unroll
        for (int reg = 0; reg < 4; ++reg) {
            int gm = by * 128 + wm + i * 16 + rb + reg;
#pragma unroll
            for (int j = 0; j < 4; ++j) {
                int gn = bx * 128 + wn + j * 16 + cb;
                Cp[(size_t)gm * ldc + gn] = f2bf(acc[i][j][reg] * scale);
            }
        }
}

// ---------------------------------------------------------------------------
// r8 merged prep + xt (one launch). blocks [0,768) prep; [768,1792) xt.
// ---------------------------------------------------------------------------
__global__ __launch_bounds__(256) void k_px(const float* __restrict__ wq,
                                            const float* __restrict__ wk,
                                            const float* __restrict__ wv,
                                            const float* __restrict__ wo,
                                            u16* __restrict__ Wqkv, u16* __restrict__ WoT,
                                            const float* __restrict__ x,
                                            u16* __restrict__ Xt)
{
    __shared__ float ls[128 * 65];
    const int id = blockIdx.x;
    if (id < 768) {
        int idx = id * 256 + threadIdx.x;
        if (idx < 49152) {
            const float* w = idx < 16384 ? wq : (idx < 32768 ? wk : wv);
            Wqkv[idx] = f2bf(w[idx & 16383]);
        }
        int j = idx - 49152;
        if (j >= 0 && j < 147456) {
            int tap = j / 16384, rem = j % 16384;  // rem = cout*128+cin
            WoT[j] = f2bf(wo[(size_t)rem * 9 + tap]);
        }
        return;
    }
    const int b2 = id - 768;
    const int n = b2 >> 6, pix0 = (b2 & 63) * 64;
#pragma unroll
    for (int rep = 0; rep < 32; ++rep) {
        int idx = rep * 256 + threadIdx.x;
        int cin = idx >> 6, p = idx & 63;
        ls[cin * 65 + p] = x[((size_t)n * Dc + cin) * PIX + pix0 + p];
    }
    __syncthreads();
#pragma unroll
    for (int rep = 0; rep < 32; ++rep) {
        int idx = rep * 256 + threadIdx.x;
        int p = idx >> 7, cin = idx & 127;
        Xt[((size_t)n * PIX + pix0 + p) * Dc + cin] = f2bf(ls[cin * 65 + p]);
    }
}

// ---------------------------------------------------------------------------
// Fused QKV GEMM; Q/K scattered directly into patched layouts (both scales).
// grid (32 pixtiles, 3 mt, 16 imgs) = 1536 blocks.
// ---------------------------------------------------------------------------
__global__ __launch_bounds__(256) void k_qkv_mfma(const u16* __restrict__ Wqkv,
                                                  const u16* __restrict__ Xt,
                                                  const float* __restrict__ bq,
                                                  const float* __restrict__ bk,
                                                  const float* __restrict__ bv,
                                                  u16* __restrict__ Qp0, u16* __restrict__ Kp0,
                                                  u16* __restrict__ Qp1, u16* __restrict__ Kp1,
                                                  u16* __restrict__ v_bf)
{
    __shared__ u16 lAs[8192], lBs[8192];
    const int tid = threadIdx.x, wave = tid >> 6, lane = tid & 63;
    const int mt = blockIdx.y, n = blockIdx.z, px0 = blockIdx.x * 128;
    f32x4 acc[4][4];
#pragma unroll
    for (int i = 0; i < 4; ++i)
#pragma unroll
        for (int j = 0; j < 4; ++j) acc[i][j] = (f32x4){0.f, 0.f, 0.f, 0.f};
    mfma_nt(Wqkv + (size_t)mt * 128 * 128, 128,
            Xt + ((size_t)n * PIX + px0) * 128, 128, 4, wave, lane, lAs, lBs, acc);
    const int wm = (wave >> 1) * 64, wn = (wave & 1) * 64;
    const int rb = (lane >> 4) * 4, cb = lane & 15;
    const int bi = n >> 3, ti = n & 7;
    if (mt < 2) {
        const float* bp = (mt == 0) ? bq : bk;
        u16* d0 = (mt == 0) ? Qp0 : Kp0;
        u16* d1 = (mt == 0) ? Qp1 : Kp1;
#pragma unroll
        for (int i = 0; i < 4; ++i)
#pragma unroll
            for (int reg = 0; reg < 4; ++reg) {
                int c = wm + i * 16 + rb + reg;          // 0..127
                float bias = bp[c];
#pragma unroll
                for (int j = 0; j < 4; ++j) {
                    int pix = px0 + wn + j * 16 + cb;
                    int y = pix >> 6, x = pix & 63;
                    u16 val = f2bf(acc[i][j][reg] + bias);
                    if (c < 64) {                         // scale 0 (ps=4)
                        int l = ti * 256 + (y >> 2) * 16 + (x >> 2);
                        int f = c * 16 + (y & 3) * 4 + (x & 3);
                        d0[((size_t)bi * 2048 + l) * 1024 + f] = val;
                    } else {                              // scale 1 (ps=8)
                        int l = ti * 64 + (y >> 3) * 8 + (x >> 3);
                        int f = (c - 64) * 64 + (y & 7) * 8 + (x & 7);
                        d1[((size_t)bi * 512 + l) * 4096 + f] = val;
                    }
                }
            }
    } else {
#pragma unroll
        for (int i = 0; i < 4; ++i)
#pragma unroll
            for (int reg = 0; reg < 4; ++reg) {
                int c = wm + i * 16 + rb + reg;
                float bias = bv[c];
#pragma unroll
                for (int j = 0; j < 4; ++j) {
                    int pix = px0 + wn + j * 16 + cb;
                    v_bf[((size_t)n * Dc + c) * PIX + pix] = f2bf(acc[i][j][reg] + bias);
                }
            }
    }
}

// ---------------------------------------------------------------------------
// FUSED k_vdw + k_depth (r10 LDS-light form; accepted at ~66us after three
// overlap attempts all landed at the serial sum -- parked permanently).
// ---------------------------------------------------------------------------
__global__ __launch_bounds__(256) void k_fuse(const float* __restrict__ X,
                                              const float* __restrict__ wvle,
                                              const float* __restrict__ bvle,
                                              const u16* __restrict__ v_bf,
                                              u16* __restrict__ Vt0,
                                              u16* __restrict__ Vt1,
                                              const float* __restrict__ dm,
                                              const float* __restrict__ wd1,
                                              const float* __restrict__ bd1,
                                              const float* __restrict__ wd2,
                                              float* __restrict__ part)
{
    __shared__ u16 lv[64 * 65];
    const int id = blockIdx.x;
    const int sub = id >> 1;
    const int tid = threadIdx.x;
    if ((id & 1) == 0) {
        // ---------------- vdw role (register rolling window, no x LDS) -----
        const int c = sub & 127, n = sub >> 7;
        const int bi = n >> 3, ti = n & 7;
        const float* xp = X + ((size_t)n * Dc + c) * PIX;
        float w[9];
#pragma unroll
        for (int t = 0; t < 9; ++t) w[t] = wvle[c * 9 + t];   // uniform -> s_load
        const float bias = bvle[c];
        const int x = tid & 63, y0 = (tid >> 6) * 16;
        const bool xl = (x > 0), xr = (x < 63);
        const u16* vp = v_bf + ((size_t)n * Dc + c) * PIX;
        // R[row][{l,c,r}] rolling window; neighbors via shuffles (lane == x).
        float R[3][3];
        auto ldrow = [&](int yy, float* dst) {
            float cc = (yy >= 0 && yy < 64) ? xp[yy * 64 + x] : 0.f; // wave-uniform cond
            float lu = __shfl_up(cc, 1);
            float rd = __shfl_down(cc, 1);
            dst[0] = xl ? lu : 0.f;
            dst[1] = cc;
            dst[2] = xr ? rd : 0.f;
        };
        ldrow(y0 - 1, R[0]);
        ldrow(y0,     R[1]);
#pragma unroll
        for (int r = 0; r < 16; ++r) {
            const int y = y0 + r;
            ldrow(y + 1, R[2]);
            float s = bias;
            s += w[0] * R[0][0] + w[1] * R[0][1] + w[2] * R[0][2];
            s += w[3] * R[1][0] + w[4] * R[1][1] + w[5] * R[1][2];
            s += w[6] * R[2][0] + w[7] * R[2][1] + w[8] * R[2][2];
            lv[y * 65 + x] = f2bf(bf2f(vp[y * 64 + x]) + s);
            R[0][0] = R[1][0]; R[0][1] = R[1][1]; R[0][2] = R[1][2];
            R[1][0] = R[2][0]; R[1][1] = R[2][1]; R[1][2] = R[2][2];
        }
        __syncthreads();
        if (c < 64) {                             // scale 0: ps=4, F=1024, L=2048
            const int fsub = tid >> 4;            // = (y&3)*4 + (x&3)
            const int py = fsub >> 2, px = fsub & 3;
            const int oh = tid & 15;
            u16 buf[16];
#pragma unroll
            for (int ow = 0; ow < 16; ++ow)
                buf[ow] = lv[(oh * 4 + py) * 65 + ow * 4 + px];
            size_t dst = ((size_t)bi * 1024 + (c * 16 + fsub)) * 2048 + ti * 256 + oh * 16;
            *(uint4*)&Vt0[dst]     = *(const uint4*)&buf[0];
            *(uint4*)&Vt0[dst + 8] = *(const uint4*)&buf[8];
        } else {                                  // scale 1: ps=8, F=4096, L=512
            const int fsub = tid >> 2;            // = (y&7)*8 + (x&7)
            const int py = fsub >> 3, px = fsub & 7;
            const int l0 = (tid & 3) * 16;
            u16 buf[16];
#pragma unroll
            for (int e = 0; e < 16; ++e) {
                int l = l0 + e, oh = l >> 3, ow = l & 7;
                buf[e] = lv[(oh * 8 + py) * 65 + ow * 8 + px];
            }
            size_t dst = ((size_t)bi * 4096 + ((c - 64) * 64 + fsub)) * 512 + ti * 64 + l0;
            *(uint4*)&Vt1[dst]     = *(const uint4*)&buf[0];
            *(uint4*)&Vt1[dst + 8] = *(const uint4*)&buf[8];
        }
    } else {
        // ---------------- depth role (r5 band version, 8-way split) --------
        const int tile = sub & 15, n = (sub >> 4) & 15, cs = sub >> 8;
        const int ty = tid >> 4, tx = tid & 15;
        const int y = (tile >> 2) * 16 + ty;
        const int x = (tile & 3) * 16 + tx;
        const float* dmp = dm + (size_t)n * 65536;
        const int gc0 = 4 * x - 4;
        const bool vy = (y > 0), vx = (x > 0);
        const int c0 = cs * 16;
        float acc = 0.f;
#pragma unroll 1
        for (int jy = 0; jy < 3; ++jy) {
            // rw[rr][i] = dm[4y-3+2jy+rr][4x-3+i], i=0..6, zero-padded.
            float rw[3][7];
#pragma unroll
            for (int rr = 0; rr < 3; ++rr) {
                const int gr = 4 * y - 3 + 2 * jy + rr;
                const float* rp = dmp + gr * 256 + gc0;
                const bool rok = (gr >= 0);
                float4 va = (rok && x > 0) ? *(const float4*)rp
                                           : make_float4(0.f, 0.f, 0.f, 0.f);
                float4 vb = rok ? *(const float4*)(rp + 4)
                                : make_float4(0.f, 0.f, 0.f, 0.f);
                rw[rr][0] = va.y; rw[rr][1] = va.z; rw[rr][2] = va.w;
                rw[rr][3] = vb.x; rw[rr][4] = vb.y; rw[rr][5] = vb.z; rw[rr][6] = vb.w;
            }
            // pin the 21-float band (small set: benign, r2/r5 verified)
#pragma unroll
            for (int rr = 0; rr < 3; ++rr)
#pragma unroll
                for (int i = 0; i < 7; ++i) asm volatile("" : "+v"(rw[rr][i]));
            const bool oky = (jy > 0) || vy;
#pragma unroll 2
            for (int cc = 0; cc < 16; ++cc) {
                const int c = c0 + cc;
                const float* w1 = wd1 + c * 9;            // uniform -> s_load
                const float* w2 = wd2 + c * 9 + jy * 3;   // uniform -> s_load
                const float b1 = bd1[c];
#pragma unroll
                for (int jx = 0; jx < 3; ++jx) {
                    float s = b1;
#pragma unroll
                    for (int ky = 0; ky < 3; ++ky)
#pragma unroll
                        for (int kx = 0; kx < 3; ++kx)
                            s += w1[ky * 3 + kx] * rw[ky][2 * jx + kx];
                    s = fmaxf(s, 0.f);
                    const bool ok = oky && ((jx > 0) || vx);
                    acc += w2[jx] * (ok ? s : 0.f);
                }
            }
        }
        part[((size_t)cs * 16 + n) * PIX + y * 64 + x] = acc;
    }
}

// Depth path finalize: dep = relu(sum of 8 channel-split partials + bd2).
__global__ void k_dfin(const float* __restrict__ part, const float* __restrict__ bd2,
                       float* __restrict__ dep)
{
    int idx = blockIdx.x * 256 + threadIdx.x;
    float s = bd2[0];
#pragma unroll
    for (int cg = 0; cg < 8; ++cg) s += part[(size_t)cg * 65536 + idx];
    dep[idx] = fmaxf(s, 0.f);
}

// ---------------------------------------------------------------------------
// Wave-parallel per-token stats; both scales merged into one launch.
// ---------------------------------------------------------------------------
template<int PS>
__device__ inline void stats_body(int sid, const float* __restrict__ mI,
                                  const float* __restrict__ dep,
                                  float* __restrict__ maskf, float* __restrict__ smed,
                                  float* __restrict__ smaxA, float* __restrict__ sminA,
                                  int outn, int L)
{
    constexpr int HW = PS * PS;              // 16 or 64
    constexpr int TPB = 256 / HW;
    const int tok = sid * TPB + (int)threadIdx.x / HW;
    const int el  = threadIdx.x % HW;
    if (tok >= Bb * L) return;
    const int bi = tok / L, l = tok % L;
    const int ti = l / (outn * outn); const int rem = l % (outn * outn);
    const int oh = rem / outn, ow = rem % outn;
    const int n = bi * Tt + ti;
    const int py = el / PS, px = el % PS;
    const size_t off = (size_t)n * PIX + (size_t)(oh * PS + py) * 64 + ow * PS + px;
    const float mv = mI[off];
    const float dv = dep[off];
    float msum = mv, vmin = dv, vmax = dv;
#pragma unroll
    for (int o = HW / 2; o > 0; o >>= 1) {
        msum += __shfl_xor(msum, o);
        vmin = fminf(vmin, __shfl_xor(vmin, o));
        vmax = fmaxf(vmax, __shfl_xor(vmax, o));
    }
    const int gbase = (threadIdx.x & 63) & ~(HW - 1);
    int cl = 0, ce = 0;
#pragma unroll
    for (int b2 = 0; b2 < HW; ++b2) {
        float vb = __shfl(dv, gbase + b2);
        cl += (vb < dv);
        ce += (vb == dv);
    }
    constexpr int kk = (HW - 1) / 2;
    if (el == 0) {
        maskf[tok] = (msum / (float)HW > 0.5f) ? 1.f : 0.f;
        smaxA[tok] = 1.f / (1.f + __expf(-vmax));
        sminA[tok] = 1.f / (1.f + __expf(-vmin));
    }
    if (cl <= kk && kk < cl + ce)
        smed[tok] = 1.f / (1.f + __expf(-dv));
}

__global__ __launch_bounds__(256) void k_stats(const float* __restrict__ mI,
                                               const float* __restrict__ dep,
                                               float* __restrict__ mk0, float* __restrict__ s00,
                                               float* __restrict__ s10, float* __restrict__ s20,
                                               float* __restrict__ mk1, float* __restrict__ s01,
                                               float* __restrict__ s11, float* __restrict__ s21)
{
    const int id = blockIdx.x;
    if (id < 256) stats_body<4>(id, mI, dep, mk0, s00, s10, s20, 16, 2048);
    else          stats_body<8>(id - 256, mI, dep, mk1, s01, s11, s21, 8, 512);
}

// ---------------------------------------------------------------------------
// r11 merged qkT: scale0 now ksplit=1 (kf=1024, 32 chunks; halves Sb0
// traffic and doubles barrier amortization; grid 512 = 2 blocks/CU).
// scale1 unchanged ksplit=16. Grid 1024 total.
// ---------------------------------------------------------------------------
__global__ __launch_bounds__(256) void k_qkT2(const u16* __restrict__ Qp0,
                                              const u16* __restrict__ Kp0,
                                              u16* __restrict__ Sb0,
                                              const u16* __restrict__ Qp1,
                                              const u16* __restrict__ Kp1,
                                              u16* __restrict__ Sb1)
{
    __shared__ u16 lAs[8192], lBs[8192];
    int id = blockIdx.x;
    const int tid = threadIdx.x;
    if (id < 512) {
        const int bx = id & 15, by = (id >> 4) & 15, bi = id >> 8;  // bi 0..1
        const u16* A = Qp0 + (size_t)bi * 2048 * 1024 + (size_t)by * 128 * 1024;
        const u16* B = Kp0 + (size_t)bi * 2048 * 1024 + (size_t)bx * 128 * 1024;
        u16* Cp = Sb0 + (size_t)bi * 2048 * 2048;
        gemm_body(A, B, 1024, 32, Cp, 2048, 0.03125f, bx, by, tid, lAs, lBs);
    } else {
        id -= 512;
        const int bx = id & 3, by = (id >> 2) & 3, z = id >> 4;    // z 0..31
        const int bi = z >> 4, ks = z & 15;
        const u16* A = Qp1 + (size_t)bi * 512 * 4096 + (size_t)by * 128 * 4096 + (size_t)ks * 256;
        const u16* B = Kp1 + (size_t)bi * 512 * 4096 + (size_t)bx * 128 * 4096 + (size_t)ks * 256;
        u16* Cp = Sb1 + ((size_t)ks * Bb + bi) * 512 * 512;
        gemm_body(A, B, 4096, 8, Cp, 512, 0.015625f, bx, by, tid, lAs, lBs);
    }
}

// ---------------------------------------------------------------------------
// 3-head softmax body (coalesced adjacent-pair mapping); merged launch.
// ---------------------------------------------------------------------------
__device__ inline float blockMax(float v, float* sh) {
#pragma unroll
    for (int o = 32; o > 0; o >>= 1) v = fmaxf(v, __shfl_down(v, o));
    __syncthreads();
    if ((threadIdx.x & 63) == 0) sh[threadIdx.x >> 6] = v;
    __syncthreads();
    return fmaxf(fmaxf(sh[0], sh[1]), fmaxf(sh[2], sh[3]));
}
__device__ inline float blockSum(float v, float* sh) {
#pragma unroll
    for (int o = 32; o > 0; o >>= 1) v += __shfl_down(v, o);
    __syncthreads();
    if ((threadIdx.x & 63) == 0) sh[threadIdx.x >> 6] = v;
    __syncthreads();
    return sh[0] + sh[1] + sh[2] + sh[3];
}

template<int NPAIR, int NSPLIT>
__device__ inline void softmax_body(const u16* __restrict__ S, u16* __restrict__ Pb,
                                    const float* __restrict__ maskf,
                                    const float* __restrict__ smed,
                                    const float* __restrict__ smaxA,
                                    const float* __restrict__ sminA,
                                    int L, int bi, int q, float* sred)
{
    const size_t pstr = (size_t)Bb * L * L;
    const u16* row = S + (size_t)bi * L * L + (size_t)q * L;
    u16* prow = Pb + (size_t)bi * L * L + (size_t)q * L;
    const float* mk  = maskf + bi * L;
    const float* s0p = smed  + bi * L;
    const float* s1p = smaxA + bi * L;
    const float* s2p = sminA + bi * L;
    const int tid = threadIdx.x;
    float a0[2 * NPAIR], a1[2 * NPAIR], a2[2 * NPAIR];
    float m0 = -3.4e38f, m1 = -3.4e38f, m2 = -3.4e38f;
#pragma unroll
    for (int e = 0; e < NPAIR; ++e) {
        int k = e * 512 + tid * 2;
        unsigned u = *(const unsigned*)&row[k];
        float sva = bf2f((u16)(u & 0xffffu));
        float svb = bf2f((u16)(u >> 16));
#pragma unroll
        for (int s2 = 1; s2 < NSPLIT; ++s2) {
            unsigned w = *(const unsigned*)&row[(size_t)s2 * pstr + k];
            sva += bf2f((u16)(w & 0xffffu));
            svb += bf2f((u16)(w >> 16));
        }
        float2 mv  = *(const float2*)&mk[k];
        float2 p0  = *(const float2*)&s0p[k];
        float2 p1  = *(const float2*)&s1p[k];
        float2 p2  = *(const float2*)&s2p[k];
        bool ma = mv.x > 0.5f, mb = mv.y > 0.5f;
        float v0a = ma ? -1e9f : sva * p0.x, v0b = mb ? -1e9f : svb * p0.y;
        float v1a = ma ? -1e9f : sva * p1.x, v1b = mb ? -1e9f : svb * p1.y;
        float v2a = ma ? -1e9f : sva * p2.x, v2b = mb ? -1e9f : svb * p2.y;
        a0[2 * e] = v0a; a0[2 * e + 1] = v0b;
        a1[2 * e] = v1a; a1[2 * e + 1] = v1b;
        a2[2 * e] = v2a; a2[2 * e + 1] = v2b;
        m0 = fmaxf(m0, fmaxf(v0a, v0b));
        m1 = fmaxf(m1, fmaxf(v1a, v1b));
        m2 = fmaxf(m2, fmaxf(v2a, v2b));
    }
    m0 = blockMax(m0, sred); m1 = blockMax(m1, sred); m2 = blockMax(m2, sred);
    float l0 = 0.f, l1 = 0.f, l2 = 0.f;
#pragma unroll
    for (int e = 0; e < 2 * NPAIR; ++e) {
        a0[e] = __expf(a0[e] - m0); l0 += a0[e];
        a1[e] = __expf(a1[e] - m1); l1 += a1[e];
        a2[e] = __expf(a2[e] - m2); l2 += a2[e];
    }
    l0 = blockSum(l0, sred); l1 = blockSum(l1, sred); l2 = blockSum(l2, sred);
    float c0 = 1.f / (3.f * l0), c1 = 1.f / (3.f * l1), c2 = 1.f / (3.f * l2);
#pragma unroll
    for (int e = 0; e < NPAIR; ++e) {
        int k = e * 512 + tid * 2;
        u16 oa = f2bf(a0[2 * e] * c0 + a1[2 * e] * c1 + a2[2 * e] * c2);
        u16 ob = f2bf(a0[2 * e + 1] * c0 + a1[2 * e + 1] * c1 + a2[2 * e + 1] * c2);
        unsigned pk = (unsigned)oa | ((unsigned)ob << 16);
        *(unsigned*)&prow[k] = pk;
    }
}

__global__ __launch_bounds__(256) void k_sm2(const u16* __restrict__ Sb0, u16* __restrict__ Pb0,
                                             const float* __restrict__ mk0, const float* __restrict__ s00,
                                             const float* __restrict__ s10, const float* __restrict__ s20,
                                             const u16* __restrict__ Sb1, u16* __restrict__ Pb1,
                                             const float* __restrict__ mk1, const float* __restrict__ s01,
                                             const float* __restrict__ s11, const float* __restrict__ s21)
{
    __shared__ float sred[4];
    int id = blockIdx.x;
    if (id < 4096) {
        const int bi = id >> 11, q = id & 2047;
        softmax_body<4, 1>(Sb0, Pb0, mk0, s00, s10, s20, 2048, bi, q, sred);
    } else {
        id -= 4096;
        const int bi = id >> 9, q = id & 511;
        softmax_body<1, 16>(Sb1, Pb1, mk1, s01, s11, s21, 512, bi, q, sred);
    }
}

// ---------------------------------------------------------------------------
// merged PV (both scales, one launch). pvsplit=2 both.
// scale0: L=2048 F=1024 kf=1024 -> 8x16x4 = 512 blocks (32 chunks)
// scale1: L= 512 F=4096 kf= 256 -> 32x4x4 = 512 blocks (8 chunks)
// ---------------------------------------------------------------------------
__global__ __launch_bounds__(256) void k_pv2(const u16* __restrict__ Pb0,
                                             const u16* __restrict__ Vt0,
                                             u16* __restrict__ Yp0,
                                             const u16* __restrict__ Pb1,
                                             const u16* __restrict__ Vt1,
                                             u16* __restrict__ Yp1)
{
    __shared__ u16 lAs[8192], lBs[8192];
    int id = blockIdx.x;
    const int tid = threadIdx.x;
    if (id < 512) {
        const int bx = id & 7, by = (id >> 3) & 15, z = id >> 7;   // z 0..3
        const int bi = z >> 1, ks = z & 1;
        const u16* A = Pb0 + (size_t)bi * 2048 * 2048 + (size_t)by * 128 * 2048 + (size_t)ks * 1024;
        const u16* B = Vt0 + (size_t)bi * 1024 * 2048 + (size_t)bx * 128 * 2048 + (size_t)ks * 1024;
        u16* Cp = Yp0 + ((size_t)ks * Bb + bi) * 2048 * 1024;
        gemm_body(A, B, 2048, 32, Cp, 1024, 1.0f, bx, by, tid, lAs, lBs);
    } else {
        id -= 512;
        const int bx = id & 31, by = (id >> 5) & 3, z = id >> 7;   // z 0..3
        const int bi = z >> 1, ks = z & 1;
        const u16* A = Pb1 + (size_t)bi * 512 * 512 + (size_t)by * 128 * 512 + (size_t)ks * 256;
        const u16* B = Vt1 + (size_t)bi * 4096 * 512 + (size_t)bx * 128 * 512 + (size_t)ks * 256;
        u16* Cp = Yp1 + ((size_t)ks * Bb + bi) * 512 * 4096;
        gemm_body(A, B, 512, 8, Cp, 4096, 1.0f, bx, by, tid, lAs, lBs);
    }
}

// ---------------------------------------------------------------------------
// merged unpatch (NSPLIT=2). 4096 blocks per scale.
// ---------------------------------------------------------------------------
template<int NSPLIT>
__device__ inline void unp_body(int sid, const u16* __restrict__ Yp, u16* __restrict__ catbT,
                                int ps, int outn, int L, int F, int cbase)
{
    size_t idx = (size_t)sid * 256 + threadIdx.x;
    size_t total = (size_t)Bb * L * F / 4;
    if (idx >= total) return;
    const size_t pstr = (size_t)Bb * L * F;
    int f0 = (int)((idx * 4) % F);
    size_t t2 = (idx * 4) / F;
    int l = (int)(t2 % L);
    int bi = (int)(t2 / L);
    size_t off = ((size_t)bi * L + l) * F + f0;
    float s[4] = {0.f, 0.f, 0.f, 0.f};
#pragma unroll
    for (int sp = 0; sp < NSPLIT; ++sp) {
        uint2 u = *(const uint2*)&Yp[(size_t)sp * pstr + off];
        s[0] += bf2f((u16)(u.x & 0xffffu));
        s[1] += bf2f((u16)(u.x >> 16));
        s[2] += bf2f((u16)(u.y & 0xffffu));
        s[3] += bf2f((u16)(u.y >> 16));
    }
    int hw = ps * ps;
    int c = cbase + f0 / hw, r0 = f0 % hw;
    int ti = l / (outn * outn); int rem = l % (outn * outn);
    int oh = rem / outn, ow = rem % outn;
    int n = bi * Tt + ti;
    int py = r0 / ps, px = r0 % ps;   // r0 4-aligned -> same row, 4 consecutive px
    size_t base = ((size_t)n * PIX + (size_t)(oh * ps + py) * 64 + ow * ps + px) * Dc + c;
#pragma unroll
    for (int e = 0; e < 4; ++e)
        catbT[base + (size_t)e * Dc] = f2bf(s[e]);
}

__global__ void k_unp2(const u16* __restrict__ Yp0, const u16* __restrict__ Yp1,
                       u16* __restrict__ catbT)
{
    const int id = blockIdx.x;
    if (id < 4096) unp_body<2>(id, Yp0, catbT, 4, 16, 2048, 1024, 0);
    else           unp_body<2>(id - 4096, Yp1, catbT, 8, 8, 512, 4096, 64);
}

// ---------------------------------------------------------------------------
// r11 output conv 3x3 as implicit NT GEMM, NO tap split: all 36 (tap,kc)
// chunks in one block (halves Cpart traffic + prologue/epilogue count).
// grid 512. bf16 [pix][cout] single partial.
// ---------------------------------------------------------------------------
__global__ __launch_bounds__(256) void k_conv_mfma(const u16* __restrict__ catbT,
                                                   const u16* __restrict__ WoT,
                                                   const u16* __restrict__ zp,
                                                   u16* __restrict__ Cpart)
{
    __shared__ u16 lAs[8192], lBs[8192];
    const int tid = threadIdx.x, wave = tid >> 6, lane = tid & 63;
    const int pix0 = blockIdx.x * 128;
    const int r = lane >> 2;
    const int kq8 = ((lane & 3) ^ ((r >> 1) & 3)) * 8;   // swizzled source seg
    int yb[2], xb[2], nn[2];
#pragma unroll
    for (int s = 0; s < 2; ++s) {
        int pg = pix0 + wave * 32 + r + s * 16;
        nn[s] = pg >> 12; yb[s] = (pg >> 6) & 63; xb[s] = pg & 63;
    }
    const u16* gb_base = WoT + (size_t)(wave * 32 + r) * 128 + kq8;

    auto stage = [&](int t, int hb) {
        const int tap = t >> 2, kc = t & 3;
        const int dy = tap / 3 - 1, dx = tap % 3 - 1;
        const u16* ga[2];
#pragma unroll
        for (int s = 0; s < 2; ++s) {
            int y = yb[s] + dy, xx = xb[s] + dx;
            bool ok = ((unsigned)y < 64u) && ((unsigned)xx < 64u);
            ga[s] = ok ? catbT + (((size_t)(nn[s] << 12) + y * 64 + xx) << 7) + kq8 + kc * 32 : zp;
        }
        const u16* gb = gb_base + tap * 16384 + kc * 32;
        GLOAD16(ga[0],     lAs + hb * 4096 + wave * 1024);
        GLOAD16(ga[1],     lAs + hb * 4096 + wave * 1024 + 512);
        GLOAD16(gb,        lBs + hb * 4096 + wave * 1024);
        GLOAD16(gb + 2048, lBs + hb * 4096 + wave * 1024 + 512);
    };

    f32x4 acc[4][4];
#pragma unroll
    for (int i = 0; i < 4; ++i)
#pragma unroll
        for (int j = 0; j < 4; ++j) acc[i][j] = (f32x4){0.f, 0.f, 0.f, 0.f};

    stage(0, 0);
    __syncthreads();
    for (int tt = 0; tt < 36; ++tt) {
        if (tt + 1 < 36) stage(tt + 1, (tt + 1) & 1);
        const int cur = (tt & 1) * 4096;
        mfma_chunk(lAs + cur, lBs + cur, wave, lane, acc);
        __syncthreads();
    }

    const int wm = (wave >> 1) * 64, wn = (wave & 1) * 64;
    const int rb = (lane >> 4) * 4, cb = lane & 15;
#pragma unroll
    for (int i = 0; i < 4; ++i)
#pragma unroll
        for (int reg = 0; reg < 4; ++reg) {
            int gm = pix0 + wm + i * 16 + rb + reg;          // global pixel
#pragma unroll
            for (int j = 0; j < 4; ++j) {
                int gn = wn + j * 16 + cb;                   // cout
                Cpart[(size_t)gm * 128 + gn] = f2bf(acc[i][j][reg]);
            }
        }
}

// ---------------------------------------------------------------------------
// Conv finalize: out = leaky(single bf16 partial + bias), NCHW fp32.
// ---------------------------------------------------------------------------
__global__ __launch_bounds__(256) void k_cfin(const u16* __restrict__ Cpart,
                                              const float* __restrict__ bo,
                                              float* __restrict__ outp)
{
    const int pg0 = blockIdx.x * 64;
    const int lane = threadIdx.x & 63, wv = threadIdx.x >> 6;
    const int pix = pg0 + lane;
    const int n = pix >> 12, p = pix & 4095;
    const u16* r0 = Cpart + (size_t)pix * 128 + wv * 32;
#pragma unroll
    for (int c4 = 0; c4 < 8; ++c4) {
        uint2 a = *(const uint2*)(r0 + c4 * 4);
        float s[4];
        s[0] = bf2f((u16)(a.x & 0xffffu));
        s[1] = bf2f((u16)(a.x >> 16));
        s[2] = bf2f((u16)(a.y & 0xffffu));
        s[3] = bf2f((u16)(a.y >> 16));
#pragma unroll
        for (int e = 0; e < 4; ++e) {
            int cout = wv * 32 + c4 * 4 + e;
            float v = s[e] + bo[cout];
            v = (v >= 0.f) ? v : 0.2f * v;
            outp[((size_t)n * Dc + cout) * PIX + p] = v;
        }
    }
}

// ---------------------------------------------------------------------------
extern "C" void kernel_launch(void* const* d_in, const int* in_sizes, int n_in,
                              void* d_out, int out_size, void* d_ws, size_t ws_size,
                              hipStream_t stream)
{
    (void)in_sizes; (void)n_in; (void)out_size; (void)ws_size;
    const float* x    = (const float*)d_in[0];
    const float* mI   = (const float*)d_in[1];
    const float* dmap = (const float*)d_in[2];
    const float* wq   = (const float*)d_in[3];
    const float* bq   = (const float*)d_in[4];
    const float* wk   = (const float*)d_in[5];
    const float* bk   = (const float*)d_in[6];
    const float* wv   = (const float*)d_in[7];
    const float* bv   = (const float*)d_in[8];
    const float* wvle = (const float*)d_in[9];
    const float* bvle = (const float*)d_in[10];
    const float* wd1  = (const float*)d_in[11];
    const float* bd1  = (const float*)d_in[12];
    const float* wd2  = (const float*)d_in[13];
    const float* bd2  = (const float*)d_in[14];
    const float* wo   = (const float*)d_in[15];
    const float* bo   = (const float*)d_in[16];

    // workspace layout (~162 MB). r11: Sb0 is 16 MB (ksplit=1), Cpart 16 MB
    // (no tap split). Aliases (timeline-checked):
    //   Yp0 @ 0x0       (16MB): over v_bf (dead after k_fuse); pv2 later
    //   Yp1 @ Sb0       (16MB): Sb0 dead after k_sm2; pv2 later
    //   Cpart @ Sb1     (16MB): Sb1 dead after k_sm2; conv after unp2; Yp1
    //                           range (0x6..0x7) disjoint from Cpart (0x7..0x8)
    char* w8 = (char*)d_ws;
    u16*   v_bf  = (u16*)(w8);                    // 16 MB [w:qkv r:fuse]
    u16*   Xt    = (u16*)(w8 + 0x1000000);        // 16 MB [w:px r:qkv]
    u16*   Yp0   = (u16*)(w8);                    // 16 MB [w:pv2 r:unp2] alias
    u16*   catbT = (u16*)(w8 + 0x2000000);        // 16 MB [w:unp2 r:conv]
    u16*   Qp0   = (u16*)(w8 + 0x3000000);        // 8 MB
    u16*   Kp0   = (u16*)(w8 + 0x3800000);
    u16*   Qp1   = (u16*)(w8 + 0x4000000);
    u16*   Kp1   = (u16*)(w8 + 0x4800000);
    u16*   Vt0   = (u16*)(w8 + 0x5000000);        // 8 MB
    u16*   Vt1   = (u16*)(w8 + 0x5800000);        // 8 MB
    u16*   Sb0   = (u16*)(w8 + 0x6000000);        // 16 MB [w:qkT2 r:sm2]
    u16*   Yp1   = (u16*)(w8 + 0x6000000);        // 16 MB [w:pv2 r:unp2] alias
    u16*   Sb1   = (u16*)(w8 + 0x7000000);        // 16 MB [w:qkT2 r:sm2]
    u16*   Cpart = (u16*)(w8 + 0x7000000);        // 16 MB [w:conv r:cfin] alias
    u16*   Pb0   = (u16*)(w8 + 0x8000000);        // 16 MB [w:sm2 r:pv2]
    u16*   Pb1   = (u16*)(w8 + 0x9000000);        // 1 MB  [w:sm2 r:pv2]
    float* part  = (float*)(w8 + 0x9100000);      // 2 MB
    float* dep   = (float*)(w8 + 0x9300000);      // 256 KB
    float* maskf = (float*)(w8 + 0x9340000);
    float* smed  = (float*)(w8 + 0x9344000);
    float* smaxA = (float*)(w8 + 0x9348000);
    float* sminA = (float*)(w8 + 0x934C000);
    float* mk1   = (float*)(w8 + 0x9350000);
    float* sm1a  = (float*)(w8 + 0x9354000);
    float* sm1b  = (float*)(w8 + 0x9358000);
    float* sm1c  = (float*)(w8 + 0x935C000);
    u16*   Wqkv  = (u16*)(w8 + 0x9360000);        // 96 KB
    u16*   WoT   = (u16*)(w8 + 0x9378000);        // 288 KB
    u16*   zp    = (u16*)(w8 + 0x93C0000);
    float* outp  = (float*)d_out;

    hipMemcpyAsync(outp + 8388608, dmap, (size_t)16 * 65536 * sizeof(float),
                   hipMemcpyDeviceToDevice, stream);
    hipMemsetAsync(zp, 0, 256, stream);

    dim3 blk(256);
    k_px<<<dim3(1792), blk, 0, stream>>>(wq, wk, wv, wo, Wqkv, WoT, x, Xt);
    k_qkv_mfma<<<dim3(32, 3, 16), blk, 0, stream>>>(Wqkv, Xt, bq, bk, bv,
                                                    Qp0, Kp0, Qp1, Kp1, v_bf);

    // fused vdw + depth (accepted at ~66us)
    k_fuse<<<dim3(4096), blk, 0, stream>>>(x, wvle, bvle, v_bf, Vt0, Vt1,
                                           dmap, wd1, bd1, wd2, part);
    k_dfin<<<dim3(256), blk, 0, stream>>>(part, bd2, dep);

    // merged attention pipeline (both scales per launch)
    k_stats<<<dim3(512), blk, 0, stream>>>(mI, dep, maskf, smed, smaxA, sminA,
                                           mk1, sm1a, sm1b, sm1c);
    k_qkT2<<<dim3(1024), blk, 0, stream>>>(Qp0, Kp0, Sb0, Qp1, Kp1, Sb1);
    k_sm2<<<dim3(5120), blk, 0, stream>>>(Sb0, Pb0, maskf, smed, smaxA, sminA,
                                          Sb1, Pb1, mk1, sm1a, sm1b, sm1c);
    k_pv2<<<dim3(1024), blk, 0, stream>>>(Pb0, Vt0, Yp0, Pb1, Vt1, Yp1);
    k_unp2<<<dim3(8192), blk, 0, stream>>>(Yp0, Yp1, catbT);

    k_conv_mfma<<<dim3(512), blk, 0, stream>>>(catbT, WoT, zp, Cpart);
    k_cfin<<<dim3(1024), blk, 0, stream>>>(Cpart, bo, outp);
}